// Round 1
// baseline (803.936 us; speedup 1.0000x reference)
//
#include <hip/hip_runtime.h>
#include <hip/hip_bf16.h>

// SPIL layer: B=8, N=4096, K=32, C=128, H=64, P=32
// Strategy: fused [theta|z] bf16 MFMA GEMM over neighbor_features (512MB stream),
// epilogue does r_f dot + pos MLP + mask + softmax + weighted sum per (n).

#define Bq 8
#define Nq 4096
#define Kq 32
#define Cq 128
#define Hq 64

typedef __bf16 bf16x8 __attribute__((ext_vector_type(8)));
typedef float  f32x4  __attribute__((ext_vector_type(4)));

__device__ __forceinline__ unsigned short f2bf(float f) {
  __hip_bfloat16 h = __float2bfloat16(f);   // RNE
  return *reinterpret_cast<unsigned short*>(&h);
}
__device__ __forceinline__ float bf2f(unsigned short u) {
  return __uint_as_float(((unsigned int)u) << 16);
}

// ---------- prep 1: WcT[h][c] = (h<64 ? theta_w[c][h] : z_w[c][h-64]) as bf16 ----------
__global__ __launch_bounds__(256) void prep_w(const float* __restrict__ theta_w,
                                              const float* __restrict__ z_w,
                                              unsigned short* __restrict__ WcT) {
  int idx = blockIdx.x * 256 + threadIdx.x;   // 0..16383
  int h = idx >> 7, c = idx & 127;
  float v = (h < 64) ? theta_w[c * 64 + h] : z_w[c * 64 + (h - 64)];
  WcT[idx] = f2bf(v);
}

// ---------- prep 2: feat_i = relu(cf @ phi_w + phi_b); s_i = dot(relu(cxyz@m1+b1), psi_w[0:32]) ----------
__global__ __launch_bounds__(256) void prep_feat(
    const float* __restrict__ cf, const float* __restrict__ cxyz,
    const float* __restrict__ phi_w, const float* __restrict__ phi_b,
    const float* __restrict__ m1_w, const float* __restrict__ m1_b,
    const float* __restrict__ psi_w,
    float* __restrict__ feat_out, float* __restrict__ s_out) {
  __shared__ float phi_s[128 * 64];
  __shared__ float cf_s[8 * 128];
  const int t = threadIdx.x;
  const size_t n0 = (size_t)blockIdx.x * 8;     // grid = B*N/8 = 4096
  for (int i = t; i < 128 * 64; i += 256) phi_s[i] = phi_w[i];
  for (int i = t; i < 8 * 128; i += 256) cf_s[i] = cf[n0 * 128 + i];
  __syncthreads();
  const int h = t & 63;
  const int rg = t >> 6;                        // rows 2rg, 2rg+1
  float a0 = phi_b[h], a1 = a0;
  const float* r0 = &cf_s[(2 * rg) * 128];
  const float* r1 = &cf_s[(2 * rg + 1) * 128];
  for (int c = 0; c < 128; c++) {
    float w = phi_s[c * 64 + h];
    a0 = fmaf(r0[c], w, a0);
    a1 = fmaf(r1[c], w, a1);
  }
  feat_out[(n0 + 2 * rg) * 64 + h]     = fmaxf(a0, 0.f);
  feat_out[(n0 + 2 * rg + 1) * 64 + h] = fmaxf(a1, 0.f);
  if (t < 8) {
    size_t n = n0 + t;
    float x = cxyz[n * 3], y = cxyz[n * 3 + 1], z = cxyz[n * 3 + 2];
    float s = 0.f;
    for (int p = 0; p < 32; p++) {
      float pi = fmaxf(x * m1_w[p] + y * m1_w[32 + p] + z * m1_w[64 + p] + m1_b[p], 0.f);
      s += pi * psi_w[p];
    }
    s_out[n] = s;
  }
}

// ---------- main: per block 4 n's (128 neighbor rows) ----------
// LDS (64KB exact): phase1 Xs[128][128]bf16 (32KB) + Ws[128][128]bf16 (32KB);
// phase2 outt[128][132]bf16 (33792B) + small arrays at [33792,35968).
__global__ __launch_bounds__(256, 2) void spil_main(
    const float* __restrict__ cxyz, const float* __restrict__ nxyz,
    const float* __restrict__ nf,
    const float* __restrict__ theta_b, const float* __restrict__ m2_w,
    const float* __restrict__ m2_b, const float* __restrict__ psi_w,
    const float* __restrict__ psi_b, const float* __restrict__ z_b,
    const unsigned short* __restrict__ WcT,
    const float* __restrict__ feat_i, const float* __restrict__ s_i,
    float* __restrict__ out) {
  __shared__ __align__(16) char smem[65536];
  unsigned short* Xs   = (unsigned short*)smem;             // [128][128]
  unsigned short* Ws   = (unsigned short*)(smem + 32768);   // [128][128]
  unsigned short* outt = (unsigned short*)smem;             // [128][132]
  float* feat_s = (float*)(smem + 33792);                   // 256
  float* m2w_s  = feat_s + 256;                             // 96
  float* m2b_s  = m2w_s + 96;                               // 32
  float* psij_s = m2b_s + 32;                               // 32
  float* zb_s   = psij_s + 32;                              // 64
  float* tb_s   = zb_s + 64;                                // 64 (ends 35968)

  const int t = threadIdx.x;
  const int wave = t >> 6, lane = t & 63;
  const int lo16 = lane & 15, quad = lane >> 4;
  const size_t n0 = (size_t)blockIdx.x * 4;                 // grid = B*N/4 = 8192

  // ---- stage X: 128 rows x 128 cols fp32 -> bf16 (coalesced float4)
  const float4* xsrc = (const float4*)(nf + n0 * Kq * Cq);
  ushort4* xdst = (ushort4*)Xs;
#pragma unroll
  for (int i = 0; i < 16; i++) {
    float4 v = xsrc[t + i * 256];
    ushort4 p;
    p.x = f2bf(v.x); p.y = f2bf(v.y); p.z = f2bf(v.z); p.w = f2bf(v.w);
    xdst[t + i * 256] = p;
  }
  // ---- stage Wt (already bf16, straight copy)
  const uint4* wsrc = (const uint4*)WcT;
  uint4* wdst = (uint4*)Ws;
#pragma unroll
  for (int i = 0; i < 8; i++) wdst[t + i * 256] = wsrc[t + i * 256];
  __syncthreads();

  // ---- MFMA: wave covers 64 rows x 64 cols (4x4 tiles of 16x16x32), K=128 in 4 steps
  const int mhalf = wave & 1, nhalf = wave >> 1;
  const bf16x8* Xv = (const bf16x8*)Xs;   // idx = row*16 + k/8
  const bf16x8* Wv = (const bf16x8*)Ws;   // idx = col*16 + k/8
  f32x4 acc[4][4];
#pragma unroll
  for (int mt = 0; mt < 4; mt++)
#pragma unroll
    for (int nt = 0; nt < 4; nt++) acc[mt][nt] = (f32x4){0.f, 0.f, 0.f, 0.f};
#pragma unroll
  for (int ks = 0; ks < 4; ks++) {
    bf16x8 a[4], b[4];
#pragma unroll
    for (int mt = 0; mt < 4; mt++)
      a[mt] = Xv[(mhalf * 64 + mt * 16 + lo16) * 16 + ks * 4 + quad];
#pragma unroll
    for (int nt = 0; nt < 4; nt++)
      b[nt] = Wv[(nhalf * 64 + nt * 16 + lo16) * 16 + ks * 4 + quad];
#pragma unroll
    for (int mt = 0; mt < 4; mt++)
#pragma unroll
      for (int nt = 0; nt < 4; nt++)
        acc[mt][nt] = __builtin_amdgcn_mfma_f32_16x16x32_bf16(a[mt], b[nt], acc[mt][nt], 0, 0, 0);
  }
  __syncthreads();

  // ---- write C to LDS (bf16, stride 132) + load epilogue constants
#pragma unroll
  for (int mt = 0; mt < 4; mt++) {
    int row0 = mhalf * 64 + mt * 16 + quad * 4;
#pragma unroll
    for (int nt = 0; nt < 4; nt++) {
      int col = nhalf * 64 + nt * 16 + lo16;
#pragma unroll
      for (int r = 0; r < 4; r++)
        outt[(row0 + r) * 132 + col] = f2bf(acc[mt][nt][r]);
    }
  }
  feat_s[t] = feat_i[n0 * 64 + t];                // 4 n x 64 h = 256
  if (t < 96) m2w_s[t] = m2_w[t];
  if (t < 32) { m2b_s[t] = m2_b[t]; psij_s[t] = psi_w[32 + t]; }
  if (t < 64) { zb_s[t] = z_b[t]; tb_s[t] = theta_b[t]; }
  __syncthreads();

  // ---- epilogue: wave w handles n = n0 + w; lanes: k = lane&31, h-half = lane>>5
  const int nl = wave;
  const size_t ng = n0 + nl;
  const int k = lane & 31, half = lane >> 5;
  const int baser = nl * 32;

  // r_f = dot(feat_i, relu(theta_out + theta_b)) / sqrt(64)
  const float* fi = feat_s + nl * 64;
  const unsigned short* orow = outt + (size_t)(baser + k) * 132;
  float v = 0.f;
#pragma unroll
  for (int i = 0; i < 32; i++) {
    int h = half * 32 + i;
    float fj = fmaxf(bf2f(orow[h]) + tb_s[h], 0.f);
    v = fmaf(fj, fi[h], v);
  }
  v += __shfl_xor(v, 32);
  float r_f = v * 0.125f;

  // positional score + SPIL mask
  float cx = cxyz[ng * 3 + 0], cy = cxyz[ng * 3 + 1], cz = cxyz[ng * 3 + 2];
  const float* nxp = nxyz + (ng * Kq + (size_t)k) * 3;
  float xj = nxp[0], yj = nxp[1], zj = nxp[2];
  float sj = 0.f;
#pragma unroll
  for (int p = 0; p < 32; p++) {
    float pj = fmaxf(fmaf(xj, m2w_s[p], fmaf(yj, m2w_s[32 + p], fmaf(zj, m2w_s[64 + p], m2b_s[p]))), 0.f);
    sj = fmaf(pj, psij_s[p], sj);
  }
  float rl = fmaxf(s_i[ng] + sj + psi_b[0], 0.f);
  float dx = cx - xj, dy = cy - yj, dz = cz - zj;
  float dist = sqrtf(dx * dx + dy * dy + dz * dz);
  if (cz == zj && dist > 0.04f) rl = 0.f;   // same_frame && far -> masked

  // masked, r_l-weighted softmax over K=32 (duplicated across lane halves)
  float m = r_f;
#pragma unroll
  for (int off = 16; off; off >>= 1) m = fmaxf(m, __shfl_xor(m, off));
  float e = rl * __expf(r_f - m);
  float s = e;
#pragma unroll
  for (int off = 16; off; off >>= 1) s += __shfl_xor(s, off);
  float wgt = e / (s + 1e-8f);

  // out[n][h] = sum_k wgt_k * (z_out[k][h] + z_b[h]); lane -> h
  const int h = lane;
  const float zb = zb_s[h];
  float o = 0.f;
#pragma unroll
  for (int kk = 0; kk < 32; kk++) {
    float w = __shfl(wgt, kk);
    o = fmaf(w, bf2f(outt[(baser + kk) * 132 + 64 + h]) + zb, o);
  }
  out[ng * 64 + h] = o;
}

extern "C" void kernel_launch(void* const* d_in, const int* in_sizes, int n_in,
                              void* d_out, int out_size, void* d_ws, size_t ws_size,
                              hipStream_t stream) {
  const float* cxyz    = (const float*)d_in[0];
  const float* cf      = (const float*)d_in[1];
  const float* nxyz    = (const float*)d_in[2];
  const float* nf      = (const float*)d_in[3];
  const float* phi_w   = (const float*)d_in[4];
  const float* phi_b   = (const float*)d_in[5];
  const float* theta_w = (const float*)d_in[6];
  const float* theta_b = (const float*)d_in[7];
  const float* m1_w    = (const float*)d_in[8];
  const float* m1_b    = (const float*)d_in[9];
  const float* m2_w    = (const float*)d_in[10];
  const float* m2_b    = (const float*)d_in[11];
  const float* psi_w   = (const float*)d_in[12];
  const float* psi_b   = (const float*)d_in[13];
  const float* z_w     = (const float*)d_in[14];
  const float* z_b     = (const float*)d_in[15];
  float* outp = (float*)d_out;

  // workspace: WcT (32KB) | feat_i (8MB) | s_i (128KB)  ~= 8.55MB total
  char* ws = (char*)d_ws;
  unsigned short* WcT = (unsigned short*)ws;
  float* feat = (float*)(ws + 32768);
  float* s_i  = (float*)(ws + 32768 + (size_t)Bq * Nq * 64 * 4);

  prep_w<<<64, 256, 0, stream>>>(theta_w, z_w, WcT);
  prep_feat<<<(Bq * Nq) / 8, 256, 0, stream>>>(cf, cxyz, phi_w, phi_b, m1_w, m1_b, psi_w, feat, s_i);
  spil_main<<<(Bq * Nq) / 4, 256, 0, stream>>>(cxyz, nxyz, nf, theta_b, m2_w, m2_b, psi_w, psi_b,
                                               z_b, WcT, feat, s_i, outp);
}

// Round 2
// 746.877 us; speedup vs baseline: 1.0764x; 1.0764x over previous
//
#include <hip/hip_runtime.h>
#include <hip/hip_bf16.h>

// SPIL layer: B=8, N=4096, K=32, C=128, H=64, P=32
// R2: XOR-swizzled X tile in LDS (kills 16-way ds_read_b128 conflicts),
//     W fragments in registers from global (L2-resident 32KB) -> LDS 35KB,
//     3 blocks/CU; prep_feat replaced by MFMA phi-GEMM.

#define Bq 8
#define Nq 4096
#define Kq 32
#define Cq 128
#define Hq 64

typedef __bf16 bf16x8 __attribute__((ext_vector_type(8)));
typedef float  f32x4  __attribute__((ext_vector_type(4)));

__device__ __forceinline__ unsigned short f2bf(float f) {
  __hip_bfloat16 h = __float2bfloat16(f);   // RNE
  return *reinterpret_cast<unsigned short*>(&h);
}
__device__ __forceinline__ float bf2f(unsigned short u) {
  return __uint_as_float(((unsigned int)u) << 16);
}

// ---------- prep 1: WcT[h][c] = [theta|z]^T bf16 ; phiT[h][c] = phi^T bf16 ----------
__global__ __launch_bounds__(256) void prep_w(const float* __restrict__ theta_w,
                                              const float* __restrict__ z_w,
                                              const float* __restrict__ phi_w,
                                              unsigned short* __restrict__ WcT,
                                              unsigned short* __restrict__ phiT) {
  int idx = blockIdx.x * 256 + threadIdx.x;   // 0..24575
  if (idx < 16384) {
    int h = idx >> 7, c = idx & 127;
    float v = (h < 64) ? theta_w[c * 64 + h] : z_w[c * 64 + (h - 64)];
    WcT[idx] = f2bf(v);
  } else {
    int i2 = idx - 16384;                     // 0..8191
    int h = i2 >> 7, c = i2 & 127;
    phiT[i2] = f2bf(phi_w[c * 64 + h]);
  }
}

// ---------- prep 2: phi GEMM: feat = relu(cf @ phi_w + phi_b), + s_i ----------
// 256 blocks x 256 thr; 128 n-rows per block; swizzled LDS tile; phiT frags in regs.
__global__ __launch_bounds__(256) void phi_gemm(
    const float* __restrict__ cf, const float* __restrict__ cxyz,
    const unsigned short* __restrict__ phiT, const float* __restrict__ phi_b,
    const float* __restrict__ m1_w, const float* __restrict__ m1_b,
    const float* __restrict__ psi_w,
    float* __restrict__ feat_out, float* __restrict__ s_out) {
  __shared__ __align__(16) unsigned short Xs[128 * 128];
  const int t = threadIdx.x;
  const int wave = t >> 6, lane = t & 63;
  const int lo16 = lane & 15, quad = lane >> 4;
  const size_t n0 = (size_t)blockIdx.x * 128;

  // B-fragments (phiT rows 0..63) from global, issued before staging
  bf16x8 wf[4][4];
#pragma unroll
  for (int ks = 0; ks < 4; ks++)
#pragma unroll
    for (int nt = 0; nt < 4; nt++)
      wf[ks][nt] = *(const bf16x8*)(phiT + (size_t)(nt * 16 + lo16) * 128 + ks * 32 + quad * 8);

  // stage cf tile fp32->bf16, XOR-swizzled granules
  const float4* xsrc = (const float4*)(cf + n0 * Cq);
  ushort4* xdst4 = (ushort4*)Xs;
#pragma unroll
  for (int i = 0; i < 16; i++) {
    int j = t + i * 256;
    float4 v = xsrc[j];
    int r = j >> 5, w = j & 31;
    int g = w >> 1, hf = w & 1;
    int p = g ^ (r & 15);
    ushort4 pk;
    pk.x = f2bf(v.x); pk.y = f2bf(v.y); pk.z = f2bf(v.z); pk.w = f2bf(v.w);
    xdst4[r * 32 + p * 2 + hf] = pk;
  }
  __syncthreads();

  // MFMA: wave covers rows wave*32..+31 (mt 0..1) x cols 0..63 (nt 0..3)
  f32x4 acc[2][4];
#pragma unroll
  for (int mt = 0; mt < 2; mt++)
#pragma unroll
    for (int nt = 0; nt < 4; nt++) acc[mt][nt] = (f32x4){0.f, 0.f, 0.f, 0.f};
#pragma unroll
  for (int ks = 0; ks < 4; ks++) {
    int p = (ks * 4 + quad) ^ lo16;
    bf16x8 a[2];
#pragma unroll
    for (int mt = 0; mt < 2; mt++) {
      int row = wave * 32 + mt * 16 + lo16;
      a[mt] = *(const bf16x8*)(Xs + row * 128 + p * 8);
    }
#pragma unroll
    for (int mt = 0; mt < 2; mt++)
#pragma unroll
      for (int nt = 0; nt < 4; nt++)
        acc[mt][nt] = __builtin_amdgcn_mfma_f32_16x16x32_bf16(a[mt], wf[ks][nt], acc[mt][nt], 0, 0, 0);
  }

  // epilogue: relu + bias, C layout col=lane&15,row=quad*4+reg
#pragma unroll
  for (int mt = 0; mt < 2; mt++)
#pragma unroll
    for (int nt = 0; nt < 4; nt++) {
      int h = nt * 16 + lo16;
      float b = phi_b[h];
#pragma unroll
      for (int r = 0; r < 4; r++) {
        int row = wave * 32 + mt * 16 + quad * 4 + r;
        feat_out[(n0 + row) * 64 + h] = fmaxf(acc[mt][nt][r] + b, 0.f);
      }
    }

  // s_i for the block's 128 n's
  if (t < 128) {
    size_t n = n0 + t;
    float x = cxyz[n * 3], y = cxyz[n * 3 + 1], z = cxyz[n * 3 + 2];
    float s = 0.f;
#pragma unroll 4
    for (int p = 0; p < 32; p++) {
      float pi = fmaxf(fmaf(x, m1_w[p], fmaf(y, m1_w[32 + p], fmaf(z, m1_w[64 + p], m1_b[p]))), 0.f);
      s = fmaf(pi, psi_w[p], s);
    }
    s_out[n] = s;
  }
}

// ---------- main: per block 4 n's (128 neighbor rows) ----------
// LDS 35968B: phase1 Xs[128][128]bf16 swizzled (32KB);
// phase2 outt[128][132]bf16 (33792B, overlaps Xs) + small arrays [33792,35968).
__global__ __launch_bounds__(256, 3) void spil_main(
    const float* __restrict__ cxyz, const float* __restrict__ nxyz,
    const float* __restrict__ nf,
    const float* __restrict__ theta_b, const float* __restrict__ m2_w,
    const float* __restrict__ m2_b, const float* __restrict__ psi_w,
    const float* __restrict__ psi_b, const float* __restrict__ z_b,
    const unsigned short* __restrict__ WcT,
    const float* __restrict__ feat_i, const float* __restrict__ s_i,
    float* __restrict__ out) {
  __shared__ __align__(16) char smem[35968];
  unsigned short* Xs   = (unsigned short*)smem;             // [128][128] swizzled
  unsigned short* outt = (unsigned short*)smem;             // [128][132]
  float* feat_s = (float*)(smem + 33792);                   // 256
  float* m2w_s  = feat_s + 256;                             // 96
  float* m2b_s  = m2w_s + 96;                               // 32
  float* psij_s = m2b_s + 32;                               // 32
  float* zb_s   = psij_s + 32;                              // 64
  float* tb_s   = zb_s + 64;                                // 64 (ends 35968)

  const int t = threadIdx.x;
  const int wave = t >> 6, lane = t & 63;
  const int lo16 = lane & 15, quad = lane >> 4;
  const size_t n0 = (size_t)blockIdx.x * 4;                 // grid = B*N/4 = 8192

  // ---- W fragments from global (L2-resident 32KB), issued first
  const int mhalf = wave & 1, nhalf = wave >> 1;
  bf16x8 wf[4][4];
#pragma unroll
  for (int ks = 0; ks < 4; ks++)
#pragma unroll
    for (int nt = 0; nt < 4; nt++)
      wf[ks][nt] = *(const bf16x8*)(WcT + (size_t)(nhalf * 64 + nt * 16 + lo16) * 128 + ks * 32 + quad * 8);

  // ---- stage X: 128 rows x 128 cols fp32 -> bf16, XOR-swizzled granules
  const float4* xsrc = (const float4*)(nf + n0 * Kq * Cq);
  ushort4* xdst4 = (ushort4*)Xs;
#pragma unroll
  for (int i = 0; i < 16; i++) {
    int j = t + i * 256;
    float4 v = xsrc[j];
    int r = j >> 5, w = j & 31;
    int g = w >> 1, hf = w & 1;
    int p = g ^ (r & 15);
    ushort4 pk;
    pk.x = f2bf(v.x); pk.y = f2bf(v.y); pk.z = f2bf(v.z); pk.w = f2bf(v.w);
    xdst4[r * 32 + p * 2 + hf] = pk;
  }
  __syncthreads();

  // ---- MFMA: wave covers 64 rows x 64 cols (4x4 tiles of 16x16x32), K=128
  f32x4 acc[4][4];
#pragma unroll
  for (int mt = 0; mt < 4; mt++)
#pragma unroll
    for (int nt = 0; nt < 4; nt++) acc[mt][nt] = (f32x4){0.f, 0.f, 0.f, 0.f};
#pragma unroll
  for (int ks = 0; ks < 4; ks++) {
    int p = (ks * 4 + quad) ^ lo16;
    bf16x8 a[4];
#pragma unroll
    for (int mt = 0; mt < 4; mt++) {
      int row = mhalf * 64 + mt * 16 + lo16;
      a[mt] = *(const bf16x8*)(Xs + row * 128 + p * 8);
    }
#pragma unroll
    for (int mt = 0; mt < 4; mt++)
#pragma unroll
      for (int nt = 0; nt < 4; nt++)
        acc[mt][nt] = __builtin_amdgcn_mfma_f32_16x16x32_bf16(a[mt], wf[ks][nt], acc[mt][nt], 0, 0, 0);
  }
  __syncthreads();   // Xs dead; outt overlaps it

  // ---- write C to LDS (bf16, stride 132) + load epilogue constants
#pragma unroll
  for (int mt = 0; mt < 4; mt++) {
    int row0 = mhalf * 64 + mt * 16 + quad * 4;
#pragma unroll
    for (int nt = 0; nt < 4; nt++) {
      int col = nhalf * 64 + nt * 16 + lo16;
#pragma unroll
      for (int r = 0; r < 4; r++)
        outt[(row0 + r) * 132 + col] = f2bf(acc[mt][nt][r]);
    }
  }
  feat_s[t] = feat_i[n0 * 64 + t];                // 4 n x 64 h = 256
  if (t < 96) m2w_s[t] = m2_w[t];
  if (t < 32) { m2b_s[t] = m2_b[t]; psij_s[t] = psi_w[32 + t]; }
  if (t < 64) { zb_s[t] = z_b[t]; tb_s[t] = theta_b[t]; }
  __syncthreads();

  // ---- epilogue: wave w handles n = n0 + w; lanes: k = lane&31, h-half = lane>>5
  const int nl = wave;
  const size_t ng = n0 + nl;
  const int k = lane & 31, half = lane >> 5;
  const int baser = nl * 32;

  // r_f = dot(feat_i, relu(theta_out + theta_b)) / sqrt(64)
  const float* fi = feat_s + nl * 64;
  const unsigned short* orow = outt + (size_t)(baser + k) * 132;
  float v = 0.f;
#pragma unroll
  for (int i = 0; i < 32; i++) {
    int h = half * 32 + i;
    float fj = fmaxf(bf2f(orow[h]) + tb_s[h], 0.f);
    v = fmaf(fj, fi[h], v);
  }
  v += __shfl_xor(v, 32);
  float r_f = v * 0.125f;

  // positional score + SPIL mask
  float cx = cxyz[ng * 3 + 0], cy = cxyz[ng * 3 + 1], cz = cxyz[ng * 3 + 2];
  const float* nxp = nxyz + (ng * Kq + (size_t)k) * 3;
  float xj = nxp[0], yj = nxp[1], zj = nxp[2];
  float sj = 0.f;
#pragma unroll
  for (int p = 0; p < 32; p++) {
    float pj = fmaxf(fmaf(xj, m2w_s[p], fmaf(yj, m2w_s[32 + p], fmaf(zj, m2w_s[64 + p], m2b_s[p]))), 0.f);
    sj = fmaf(pj, psij_s[p], sj);
  }
  float rl = fmaxf(s_i[ng] + sj + psi_b[0], 0.f);
  float dx = cx - xj, dy = cy - yj, dz = cz - zj;
  float dist = sqrtf(dx * dx + dy * dy + dz * dz);
  if (cz == zj && dist > 0.04f) rl = 0.f;   // same_frame && far -> masked

  // masked, r_l-weighted softmax over K=32 (duplicated across lane halves)
  float m = r_f;
#pragma unroll
  for (int off = 16; off; off >>= 1) m = fmaxf(m, __shfl_xor(m, off));
  float e = rl * __expf(r_f - m);
  float s = e;
#pragma unroll
  for (int off = 16; off; off >>= 1) s += __shfl_xor(s, off);
  float wgt = e / (s + 1e-8f);

  // out[n][h] = sum_k wgt_k * (z_out[k][h] + z_b[h]); lane -> h
  const int h = lane;
  const float zb = zb_s[h];
  float o = 0.f;
#pragma unroll
  for (int kk = 0; kk < 32; kk++) {
    float w = __shfl(wgt, kk);
    o = fmaf(w, bf2f(outt[(baser + kk) * 132 + 64 + h]) + zb, o);
  }
  out[ng * 64 + h] = o;
}

extern "C" void kernel_launch(void* const* d_in, const int* in_sizes, int n_in,
                              void* d_out, int out_size, void* d_ws, size_t ws_size,
                              hipStream_t stream) {
  const float* cxyz    = (const float*)d_in[0];
  const float* cf      = (const float*)d_in[1];
  const float* nxyz    = (const float*)d_in[2];
  const float* nf      = (const float*)d_in[3];
  const float* phi_w   = (const float*)d_in[4];
  const float* phi_b   = (const float*)d_in[5];
  const float* theta_w = (const float*)d_in[6];
  const float* theta_b = (const float*)d_in[7];
  const float* m1_w    = (const float*)d_in[8];
  const float* m1_b    = (const float*)d_in[9];
  const float* m2_w    = (const float*)d_in[10];
  const float* m2_b    = (const float*)d_in[11];
  const float* psi_w   = (const float*)d_in[12];
  const float* psi_b   = (const float*)d_in[13];
  const float* z_w     = (const float*)d_in[14];
  const float* z_b     = (const float*)d_in[15];
  float* outp = (float*)d_out;

  // workspace: WcT (32KB) | phiT (16KB) | feat_i (8MB) | s_i (128KB)
  char* ws = (char*)d_ws;
  unsigned short* WcT  = (unsigned short*)ws;
  unsigned short* phiT = (unsigned short*)(ws + 32768);
  float* feat = (float*)(ws + 49152);
  float* s_i  = (float*)(ws + 49152 + (size_t)Bq * Nq * 64 * 4);

  prep_w<<<96, 256, 0, stream>>>(theta_w, z_w, phi_w, WcT, phiT);
  phi_gemm<<<(Bq * Nq) / 128, 256, 0, stream>>>(cf, cxyz, phiT, phi_b, m1_w, m1_b, psi_w, feat, s_i);
  spil_main<<<(Bq * Nq) / 4, 256, 0, stream>>>(cxyz, nxyz, nf, theta_b, m2_w, m2_b, psi_w, psi_b,
                                               z_b, WcT, feat, s_i, outp);
}